// Round 15
// baseline (112.830 us; speedup 1.0000x reference)
//
#include <hip/hip_runtime.h>

#define CLS 8
#define BATCH 8
#define SPAN 1024                 // px per block -> 256 chunks/batch, 2048 blocks
#define CHUNKS 256                // N / SPAN
#define SLOTF 80                  // floats per block slot (73 used)
#define LOG2E 1.442695040888963f
#define LN2   0.693147180559945f

#define F4C(v, e) ((e) == 0 ? (v).x : (e) == 1 ? (v).y : (e) == 2 ? (v).z : (v).w)

__device__ __forceinline__ float wave_reduce(float v) {
#pragma unroll
    for (int off = 32; off > 0; off >>= 1) v += __shfl_xor(v, off);
    return v;
}

// ---------------- main: one pass; masked class-sums via LDS float atomics
// (scatter), NO 64-entry register accumulator, NO ballots, NO butterfly. ----
__global__ __launch_bounds__(256, 8) void jce_main(
    const float* __restrict__ pred, const int* __restrict__ tgt,
    float* __restrict__ part, int N)
{
    // [wave][parity][76]: entries 0..63 = S (c*8+k), 64..71 = counts, pad to 76
    // parity copy halves same-address atomic collisions; stride 76 (%32=12)
    // puts the two copies on disjoint banks.
    __shared__ float accL[4][2][76];
    __shared__ float redl[4];

    const int tid   = threadIdx.x;
    const int b     = blockIdx.x & (BATCH - 1);
    const int chunk = blockIdx.x >> 3;          // 0..255
    const int lane  = tid & 63;
    const int wv    = tid >> 6;
    const float* pb = pred + (size_t)b * CLS * N + chunk * SPAN;
    const int*   tb = tgt  + (size_t)b * N + chunk * SPAN;

    for (int j = tid; j < 4 * 2 * 76; j += 256) (&accL[0][0][0])[j] = 0.f;
    __syncthreads();

    const int4 t0 = *reinterpret_cast<const int4*>(tb + tid * 4);
    float* myacc = &accL[wv][lane & 1][0];

    // class counts: one ds_add per pixel
    atomicAdd(&myacc[64 + t0.x], 1.f);
    atomicAdd(&myacc[64 + t0.y], 1.f);
    atomicAdd(&myacc[64 + t0.z], 1.f);
    atomicAdd(&myacc[64 + t0.w], 1.f);

    float s[4] = {0.f, 0.f, 0.f, 0.f};          // per-pixel exp2 partial sums
    float4 a0, c0;

#define LDC(X, c) (X) = *reinterpret_cast<const float4*>(pb + (size_t)(c) * N + tid * 4)

#define ACCC(X, c) do {                                                         \
        _Pragma("unroll")                                                       \
        for (int _e = 0; _e < 4; ++_e) {                                        \
            const float _p = F4C((X), _e);                                      \
            const int   _t = F4C(t0, _e);                                       \
            s[_e] += exp2f(_p * LOG2E);                                         \
            atomicAdd(&myacc[(c) * 8 + _t], _p);   /* ds_add_f32, no return */  \
        }                                                                       \
    } while (0)

    LDC(a0, 0);
    LDC(c0, 1);
    ACCC(a0, 0); LDC(a0, 2);
    ACCC(c0, 1); LDC(c0, 3);
    ACCC(a0, 2); LDC(a0, 4);
    ACCC(c0, 3); LDC(c0, 5);
    ACCC(a0, 4); LDC(a0, 6);
    ACCC(c0, 5); LDC(c0, 7);
    ACCC(a0, 6);
    ACCC(c0, 7);
#undef LDC
#undef ACCC

    const float lsum = log2f(s[0]) + log2f(s[1]) + log2f(s[2]) + log2f(s[3]);
    const float lw = wave_reduce(lsum);
    if (lane == 0) redl[wv] = lw;
    __syncthreads();

    // block totals -> private slot, plain coalesced stores (no global atomics)
    float* slot = part + (size_t)(b * CHUNKS + chunk) * SLOTF;
    if (tid < 72) {
        float v = 0.f;
#pragma unroll
        for (int q = 0; q < 4; ++q) v += accL[q][0][tid] + accL[q][1][tid];
        slot[tid] = v;
    } else if (tid == 72) {
        slot[72] = (redl[0] + redl[1] + redl[2] + redl[3]) * LN2;
    }
}

// ---------------- finisher: 1 block, 1024 threads; reduces 2048 slots
// (640 KB, L2-resident) and runs the epilogue. ------------------------------
__global__ __launch_bounds__(1024) void jce_fin(
    const float* __restrict__ part, const float* __restrict__ w,
    float* __restrict__ out, int N)
{
    const int tid  = threadIdx.x;
    const int lane = tid & 63;
    const int wv   = tid >> 6;

    __shared__ float eS[BATCH][64];
    __shared__ float eN[BATCH][CLS];
    __shared__ float eLp[BATCH];
    __shared__ float eCe;

    if (tid < BATCH * SLOTF) {                  // 640 threads: (batch, column)
        const int b = tid / SLOTF, c = tid % SLOTF;
        if (c < 73) {
            const float* p = part + (size_t)(b * CHUNKS) * SLOTF + c;
            float acc = 0.f;
#pragma unroll 8
            for (int i = 0; i < CHUNKS; ++i) acc += p[(size_t)i * SLOTF];
            if (c < 64)      eS[b][c] = acc;
            else if (c < 72) eN[b][c - 64] = acc;
            else             eLp[b] = acc;
        }
    }
    __syncthreads();

    // ce = (sum lse - sum_b trace(S_b)) / (B*N)
    if (tid < 64) {
        const int bb = tid >> 3, kk = tid & 7;
        float tv = eS[bb][kk * 9];
        tv = wave_reduce(tv);
        if (tid == 0) {
            float el = 0.f;
#pragma unroll
            for (int b = 0; b < BATCH; ++b) el += eLp[b];
            eCe = (el - tv) / ((float)BATCH * (float)N);
        }
    }
    __syncthreads();

    // j[b] = -sum_{i!=k} w[i,k]*log(0.5 + 0.5*(A[i,i]-A[i,k])); out = j + ce
    if (wv < BATCH) {
        const int i = lane >> 3, k = lane & 7;
        const float A    = eS[wv][lane]  / eN[wv][k];
        const float diag = eS[wv][i * 9] / eN[wv][i];
        float term = 0.f;
        if (i != k)
            term = w[lane] * (log2f(0.5f + 0.5f * (diag - A)) * LN2);
        term = wave_reduce(term);
        if (lane == 0) out[wv] = -term + eCe;
    }
}

extern "C" void kernel_launch(void* const* d_in, const int* in_sizes, int n_in,
                              void* d_out, int out_size, void* d_ws, size_t ws_size,
                              hipStream_t stream) {
    const float* pred = (const float*)d_in[0];
    const int*   tgt  = (const int*)d_in[1];
    const float* w    = (const float*)d_in[2];
    float* out = (float*)d_out;

    const int N = in_sizes[1] / BATCH;        // H*W = 262144
    float* part = (float*)d_ws;               // 2048 * 80 floats, fully overwritten
                                              // every call (cols 73..79 unused)

    jce_main<<<dim3(BATCH * CHUNKS), dim3(256), 0, stream>>>(pred, tgt, part, N);
    jce_fin <<<dim3(1), dim3(1024), 0, stream>>>(part, w, out, N);
}

// Round 16
// 44.231 us; speedup vs baseline: 2.5509x; 2.5509x over previous
//
#include <hip/hip_runtime.h>

#define CLS 8
#define BATCH 8
#define SPAN 1024                 // px per block -> 256 chunks/batch, 2048 blocks
#define CHUNKS 256                // N / SPAN
#define SLOTF 128                 // floats per block slot (73 used)
#define LOG2E 1.442695040888963f
#define LN2   0.693147180559945f

#define F4C(v, e) ((e) == 0 ? (v).x : (e) == 1 ? (v).y : (e) == 2 ? (v).z : (v).w)

__device__ __forceinline__ float wave_reduce(float v) {
#pragma unroll
    for (int off = 32; off > 0; off >>= 1) v += __shfl_xor(v, off);
    return v;
}

// ---------------- main: K1-shaped fused pass.
// 2048 blocks, VGPR-lean (acc[8]+s[4]+t4), channel-serial staggered visits,
// 3-stage routed butterfly + one ds_add per thread per channel. -------------
__global__ __launch_bounds__(256, 8) void jce_main(
    const float* __restrict__ pred, const int* __restrict__ tgt,
    float* __restrict__ part, int N)
{
    __shared__ float accL[64];           // S[c*8+k] block totals
    __shared__ float redl[4];
    __shared__ int   redc[4][CLS];

    const int tid   = threadIdx.x;
    const int b     = blockIdx.x & (BATCH - 1);
    const int chunk = blockIdx.x >> 3;          // 0..255
    const int lane  = tid & 63;
    const int wv    = tid >> 6;
    const float* pb = pred + (size_t)b * CLS * N + chunk * SPAN;
    const int*   tb = tgt  + (size_t)b * N + chunk * SPAN;

    if (tid < 64) accL[tid] = 0.f;
    __syncthreads();

    // this thread's 4 targets, held in registers for the whole kernel
    const int4 t4 = *reinterpret_cast<const int4*>(tb + tid * 4);

    // class counts via ballot (wave-uniform SGPRs), once
    int cnt[CLS];
#pragma unroll
    for (int k = 0; k < CLS; ++k) {
        int c8 = 0;
        c8 += __popcll(__ballot(t4.x == k));
        c8 += __popcll(__ballot(t4.y == k));
        c8 += __popcll(__ballot(t4.z == k));
        c8 += __popcll(__ballot(t4.w == k));
        cnt[k] = c8;
    }

    float s[4] = {0.f, 0.f, 0.f, 0.f};          // per-pixel exp2 partial sums
    // lane l's 3-stage butterfly output is class bitrev3(l&7)
    const int e3 = ((lane & 1) << 2) | (lane & 2) | ((lane & 4) >> 2);

    float4 A, B;

#define LDCH(X, i) (X) = *reinterpret_cast<const float4*>( \
        pb + (size_t)((chunk + (i)) & 7) * N + tid * 4)

#define STEP(X, i) do {                                                         \
        float acc[8] = {0.f,0.f,0.f,0.f,0.f,0.f,0.f,0.f};                       \
        _Pragma("unroll")                                                       \
        for (int _e = 0; _e < 4; ++_e) {                                        \
            const float _p = F4C((X), _e);                                      \
            const int   _t = F4C(t4, _e);                                       \
            s[_e] += exp2f(_p * LOG2E);                                         \
            _Pragma("unroll")                                                   \
            for (int _k = 0; _k < CLS; ++_k)                                    \
                acc[_k] += (_t == _k) ? _p : 0.f;                               \
        }                                                                       \
        /* 3-stage routed reduce within 8-lane groups */                        \
        _Pragma("unroll")                                                       \
        for (int _s = 0; _s < 3; ++_s) {                                        \
            const int _d = 1 << _s;                                             \
            const int _h = 4 >> _s;                                             \
            const bool _hi = (lane & _d) != 0;                                  \
            _Pragma("unroll")                                                   \
            for (int _j = 0; _j < _h; ++_j) {                                   \
                const float _keep = _hi ? acc[_j + _h] : acc[_j];               \
                const float _send = _hi ? acc[_j] : acc[_j + _h];               \
                acc[_j] = _keep + __shfl_xor(_send, _d);                        \
            }                                                                   \
        }                                                                       \
        atomicAdd(&accL[((chunk + (i)) & 7) * 8 + e3], acc[0]);                 \
    } while (0)

    LDCH(A, 0);
    LDCH(B, 1);
    STEP(A, 0); LDCH(A, 2);
    STEP(B, 1); LDCH(B, 3);
    STEP(A, 2); LDCH(A, 4);
    STEP(B, 3); LDCH(B, 5);
    STEP(A, 4); LDCH(A, 6);
    STEP(B, 5); LDCH(B, 7);
    STEP(A, 6);
    STEP(B, 7);
#undef LDCH
#undef STEP

    const float lsum = log2f(s[0]) + log2f(s[1]) + log2f(s[2]) + log2f(s[3]);
    const float lw = wave_reduce(lsum);
    if (lane == 0) {
        redl[wv] = lw;
#pragma unroll
        for (int k = 0; k < CLS; ++k) redc[wv][k] = cnt[k];
    }
    __syncthreads();

    // block totals -> private slot, plain coalesced stores
    float* slot = part + (size_t)(b * CHUNKS + chunk) * SLOTF;
    if (tid < 64) {
        slot[tid] = accL[tid];
    } else if (tid < 72) {
        const int k = tid - 64;
        slot[tid] = (float)(redc[0][k] + redc[1][k] + redc[2][k] + redc[3][k]);
    } else if (tid == 72) {
        slot[72] = (redl[0] + redl[1] + redl[2] + redl[3]) * LN2;
    }
}

// ---------------- reducer: 8 blocks (one per batch), coalesced column-sum of
// 256 slots x 128 cols; writes red[b][80]. -----------------------------------
__global__ __launch_bounds__(1024) void jce_red(
    const float* __restrict__ part, float* __restrict__ red)
{
    __shared__ float lds[8][128];
    const int b = blockIdx.x, t = threadIdx.x;
    const int col = t & 127, cg = t >> 7;       // 8 chunk-groups x 128 cols
    float a = 0.f;
#pragma unroll 8
    for (int i = 0; i < 32; ++i)
        a += part[(size_t)(b * CHUNKS + cg * 32 + i) * SLOTF + col];
    lds[cg][col] = a;
    __syncthreads();
    if (t < 128) {
        float v = 0.f;
#pragma unroll
        for (int g = 0; g < 8; ++g) v += lds[g][t];
        if (t < 73) red[b * 80 + t] = v;
    }
}

// ---------------- epilogue: 1 block, 512 threads (wave b handles batch b) ---
__global__ __launch_bounds__(512) void jce_epi(
    const float* __restrict__ red, const float* __restrict__ w,
    float* __restrict__ out, int N)
{
    const int tid = threadIdx.x, lane = tid & 63, wv = tid >> 6;
    __shared__ float eCe;

    if (wv == 0) {      // ce = (sum lse - sum_b trace(S_b)) / (B*N)
        const float tv = red[(lane >> 3) * 80 + (lane & 7) * 9];
        const float el = (lane < 8) ? red[lane * 80 + 72] : 0.f;
        const float trs = wave_reduce(tv);
        const float els = wave_reduce(el);
        if (lane == 0) eCe = (els - trs) / ((float)BATCH * (float)N);
    }
    __syncthreads();

    const int i = lane >> 3, k = lane & 7;
    const float A    = red[wv * 80 + lane]  / red[wv * 80 + 64 + k];
    const float diag = red[wv * 80 + i * 9] / red[wv * 80 + 64 + i];
    float term = 0.f;
    if (i != k)
        term = w[lane] * (log2f(0.5f + 0.5f * (diag - A)) * LN2);
    term = wave_reduce(term);
    if (lane == 0) out[wv] = -term + eCe;
}

extern "C" void kernel_launch(void* const* d_in, const int* in_sizes, int n_in,
                              void* d_out, int out_size, void* d_ws, size_t ws_size,
                              hipStream_t stream) {
    const float* pred = (const float*)d_in[0];
    const int*   tgt  = (const int*)d_in[1];
    const float* w    = (const float*)d_in[2];
    float* out = (float*)d_out;

    const int N = in_sizes[1] / BATCH;        // H*W = 262144

    float* part = (float*)d_ws;                               // 2048*128 floats (1 MB)
    float* red  = part + (size_t)BATCH * CHUNKS * SLOTF;      // 8*80 floats

    jce_main<<<dim3(BATCH * CHUNKS), dim3(256), 0, stream>>>(pred, tgt, part, N);
    jce_red <<<dim3(BATCH), dim3(1024), 0, stream>>>(part, red);
    jce_epi <<<dim3(1), dim3(512), 0, stream>>>(red, w, out, N);
}

// Round 17
// 29.872 us; speedup vs baseline: 3.7771x; 1.4807x over previous
//
#include <hip/hip_runtime.h>

#define CLS 8
#define BATCH 8
#define THREADS 512
#define SPAN 2048                 // px per block -> 128 chunks/batch, 1024 blocks
#define CHUNKS 128                // N / SPAN
#define SLOTF 128                 // floats per block slot (73 used)
#define LOG2E 1.442695040888963f
#define LN2   0.693147180559945f

#define F4C(v, e) ((e) == 0 ? (v).x : (e) == 1 ? (v).y : (e) == 2 ? (v).z : (v).w)

__device__ __forceinline__ float wave_reduce(float v) {
#pragma unroll
    for (int off = 32; off > 0; off >>= 1) v += __shfl_xor(v, off);
    return v;
}

// ---------------- main: single pass, K1-essence.
// 512 thr x 1024 blocks (32 waves/CU). Channel-serial 8KB runs, depth-2,
// <=2 streams in flight. Inner loop pure VALU (cndmask-add + exp2).
// Per-visit flush: 3-stage shfl butterfly + ONE plain ds_write per lane into
// a private [c][wave][group][class] slot -- no LDS atomics, no in-loop barrier.
__global__ __launch_bounds__(THREADS, 8) void jce_main(
    const float* __restrict__ pred, const int* __restrict__ tgt,
    float* __restrict__ part, int N)
{
    __shared__ float ldsPart[8 * 8 * 8 * 8];   // [c][wv][grp][k], 16 KB, each slot written once
    __shared__ float redl[8];
    __shared__ int   redc[8][CLS];

    const int tid   = threadIdx.x;
    const int b     = blockIdx.x & (BATCH - 1);
    const int chunk = blockIdx.x >> 3;          // 0..127
    const int lane  = tid & 63;
    const int wv    = tid >> 6;                 // 0..7
    const int grp   = lane >> 3;                // 0..7
    const float* pb = pred + (size_t)b * CLS * N + chunk * SPAN;
    const int*   tb = tgt  + (size_t)b * N + chunk * SPAN;

    // lane l's butterfly output is class bitrev3(l&7)
    const int e3 = ((lane & 1) << 2) | (lane & 2) | ((lane & 4) >> 2);

    // this thread's 4 targets, resident all kernel
    const int4 t4 = *reinterpret_cast<const int4*>(tb + tid * 4);

    // class counts via ballot (wave-uniform), once
    int cnt[CLS];
#pragma unroll
    for (int k = 0; k < CLS; ++k) {
        int c8 = 0;
        c8 += __popcll(__ballot(t4.x == k));
        c8 += __popcll(__ballot(t4.y == k));
        c8 += __popcll(__ballot(t4.z == k));
        c8 += __popcll(__ballot(t4.w == k));
        cnt[k] = c8;
    }

    float s[4] = {0.f, 0.f, 0.f, 0.f};          // per-pixel exp2 partial sums

    float4 A, B;

#define LDCH(X, i) (X) = *reinterpret_cast<const float4*>( \
        pb + (size_t)((chunk + (i)) & 7) * N + tid * 4)

#define STEP(X, i) do {                                                         \
        const int _c = (chunk + (i)) & 7;                                       \
        float acc[8] = {0.f,0.f,0.f,0.f,0.f,0.f,0.f,0.f};                       \
        _Pragma("unroll")                                                       \
        for (int _e = 0; _e < 4; ++_e) {                                        \
            const float _p = F4C((X), _e);                                      \
            const int   _t = F4C(t4, _e);                                       \
            s[_e] += exp2f(_p * LOG2E);                                         \
            _Pragma("unroll")                                                   \
            for (int _k = 0; _k < CLS; ++_k)                                    \
                acc[_k] += (_t == _k) ? _p : 0.f;                               \
        }                                                                       \
        /* 3-stage routed reduce within 8-lane groups */                        \
        _Pragma("unroll")                                                       \
        for (int _s = 0; _s < 3; ++_s) {                                        \
            const int _d = 1 << _s;                                             \
            const int _h = 4 >> _s;                                             \
            const bool _hi = (lane & _d) != 0;                                  \
            _Pragma("unroll")                                                   \
            for (int _j = 0; _j < _h; ++_j) {                                   \
                const float _keep = _hi ? acc[_j + _h] : acc[_j];               \
                const float _send = _hi ? acc[_j] : acc[_j + _h];               \
                acc[_j] = _keep + __shfl_xor(_send, _d);                        \
            }                                                                   \
        }                                                                       \
        ldsPart[_c * 512 + wv * 64 + grp * 8 + e3] = acc[0];  /* plain write */ \
    } while (0)

    LDCH(A, 0);
    LDCH(B, 1);
    STEP(A, 0); LDCH(A, 2);
    STEP(B, 1); LDCH(B, 3);
    STEP(A, 2); LDCH(A, 4);
    STEP(B, 3); LDCH(B, 5);
    STEP(A, 4); LDCH(A, 6);
    STEP(B, 5); LDCH(B, 7);
    STEP(A, 6);
    STEP(B, 7);
#undef LDCH
#undef STEP

    const float lsum = log2f(s[0]) + log2f(s[1]) + log2f(s[2]) + log2f(s[3]);
    const float lw = wave_reduce(lsum);
    if (lane == 0) {
        redl[wv] = lw;
#pragma unroll
        for (int k = 0; k < CLS; ++k) redc[wv][k] = cnt[k];
    }
    __syncthreads();    // the only barrier

    // block totals -> private slot, plain coalesced stores
    float* slot = part + (size_t)(b * CHUNKS + chunk) * SLOTF;
    if (tid < 64) {
        const int c = tid >> 3, k = tid & 7;
        float v = 0.f;
#pragma unroll
        for (int j = 0; j < 64; ++j)            // sum over (wv, grp)
            v += ldsPart[c * 512 + (j >> 3) * 64 + (j & 7) * 8 + k];
        slot[tid] = v;
    } else if (tid < 72) {
        const int k = tid - 64;
        int v = 0;
#pragma unroll
        for (int q = 0; q < 8; ++q) v += redc[q][k];
        slot[tid] = (float)v;
    } else if (tid == 72) {
        float v = 0.f;
#pragma unroll
        for (int q = 0; q < 8; ++q) v += redl[q];
        slot[72] = v * LN2;
    }
}

// ---------------- reducer: 8 blocks (one per batch), coalesced column-sum of
// 128 slots x 128 cols; writes red[b][80]. -----------------------------------
__global__ __launch_bounds__(1024) void jce_red(
    const float* __restrict__ part, float* __restrict__ red)
{
    __shared__ float lds[8][128];
    const int b = blockIdx.x, t = threadIdx.x;
    const int col = t & 127, cg = t >> 7;       // 8 chunk-groups x 128 cols
    float a = 0.f;
#pragma unroll 4
    for (int i = 0; i < 16; ++i)
        a += part[(size_t)(b * CHUNKS + cg * 16 + i) * SLOTF + col];
    lds[cg][col] = a;
    __syncthreads();
    if (t < 128) {
        float v = 0.f;
#pragma unroll
        for (int g = 0; g < 8; ++g) v += lds[g][t];
        if (t < 73) red[b * 80 + t] = v;
    }
}

// ---------------- epilogue: 1 block, 512 threads (wave b handles batch b) ---
__global__ __launch_bounds__(512) void jce_epi(
    const float* __restrict__ red, const float* __restrict__ w,
    float* __restrict__ out, int N)
{
    const int tid = threadIdx.x, lane = tid & 63, wv = tid >> 6;
    __shared__ float eCe;

    if (wv == 0) {      // ce = (sum lse - sum_b trace(S_b)) / (B*N)
        const float tv = red[(lane >> 3) * 80 + (lane & 7) * 9];
        const float el = (lane < 8) ? red[lane * 80 + 72] : 0.f;
        const float trs = wave_reduce(tv);
        const float els = wave_reduce(el);
        if (lane == 0) eCe = (els - trs) / ((float)BATCH * (float)N);
    }
    __syncthreads();

    const int i = lane >> 3, k = lane & 7;
    const float A    = red[wv * 80 + lane]  / red[wv * 80 + 64 + k];
    const float diag = red[wv * 80 + i * 9] / red[wv * 80 + 64 + i];
    float term = 0.f;
    if (i != k)
        term = w[lane] * (log2f(0.5f + 0.5f * (diag - A)) * LN2);
    term = wave_reduce(term);
    if (lane == 0) out[wv] = -term + eCe;
}

extern "C" void kernel_launch(void* const* d_in, const int* in_sizes, int n_in,
                              void* d_out, int out_size, void* d_ws, size_t ws_size,
                              hipStream_t stream) {
    const float* pred = (const float*)d_in[0];
    const int*   tgt  = (const int*)d_in[1];
    const float* w    = (const float*)d_in[2];
    float* out = (float*)d_out;

    const int N = in_sizes[1] / BATCH;        // H*W = 262144

    float* part = (float*)d_ws;                               // 1024*128 floats (512 KB)
    float* red  = part + (size_t)BATCH * CHUNKS * SLOTF;      // 8*80 floats

    jce_main<<<dim3(BATCH * CHUNKS), dim3(THREADS), 0, stream>>>(pred, tgt, part, N);
    jce_red <<<dim3(BATCH), dim3(1024), 0, stream>>>(part, red);
    jce_epi <<<dim3(1), dim3(512), 0, stream>>>(red, w, out, N);
}